// Round 3
// baseline (702.165 us; speedup 1.0000x reference)
//
#include <hip/hip_runtime.h>

#define N_NODES 50000
#define N_EDGES 1600000
#define NCHUNK  ((N_NODES + 255) / 256)   // 196

typedef unsigned short ushort_t;
typedef __attribute__((ext_vector_type(8))) __bf16 bf16x8;
typedef __attribute__((ext_vector_type(4))) float  f32x4;

union FU { ushort_t s[8]; bf16x8 v; };

__device__ __forceinline__ float bf2f(ushort_t u) {
    union { unsigned int i; float f; } v; v.i = ((unsigned int)u) << 16; return v.f;
}
__device__ __forceinline__ ushort_t f2bf(float f) {
    union { float f; unsigned int i; } v; v.f = f;
    unsigned int r = v.i + 0x7fffu + ((v.i >> 16) & 1u);
    return (ushort_t)(r >> 16);
}
__device__ __forceinline__ float leaky(float x, float s) { return x >= 0.f ? x : s * x; }
__device__ __forceinline__ int clampi(int x, int hi) { return (x < 0) ? 0 : (x >= hi ? 0 : x); }

// split fp32[8] -> hi/lo bf16x8 (double-bf16 activation trick)
__device__ __forceinline__ void split8(const float* x, bf16x8& hi, bf16x8& lo) {
    FU h, l;
    #pragma unroll
    for (int j = 0; j < 8; j++) {
        ushort_t hb = f2bf(x[j]);
        float hf = bf2f(hb);
        h.s[j] = hb;
        l.s[j] = f2bf(x[j] - hf);
    }
    hi = h.v; lo = l.v;
}

// ---------------- K1: histogram of src ----------------
__global__ __launch_bounds__(256) void k_hist(const int* __restrict__ src, int* __restrict__ cnt) {
    int e = blockIdx.x * 256 + threadIdx.x;
    if (e < N_EDGES) atomicAdd(&cnt[src[e]], 1);
}

// ---------------- K2: exclusive scan of cnt -> cursor ----------------
__global__ __launch_bounds__(256) void k_scan_chunk(const int* __restrict__ cnt, int* __restrict__ cursor,
                                                    int* __restrict__ blocksum) {
    __shared__ int buf[256];
    int t = threadIdx.x, i = blockIdx.x * 256 + t;
    int v = (i < N_NODES) ? cnt[i] : 0;
    buf[t] = v; __syncthreads();
    for (int off = 1; off < 256; off <<= 1) {
        int x = (t >= off) ? buf[t - off] : 0;
        __syncthreads(); buf[t] += x; __syncthreads();
    }
    int incl = buf[t];
    if (i < N_NODES) cursor[i] = incl - v;
    if (t == 255) blocksum[blockIdx.x] = incl;
}
__global__ __launch_bounds__(256) void k_scan_block(int* __restrict__ blocksum) {
    __shared__ int buf[256];
    int t = threadIdx.x;
    int v = (t < NCHUNK) ? blocksum[t] : 0;
    buf[t] = v; __syncthreads();
    for (int off = 1; off < 256; off <<= 1) {
        int x = (t >= off) ? buf[t - off] : 0;
        __syncthreads(); buf[t] += x; __syncthreads();
    }
    blocksum[t] = buf[t] - v;   // exclusive
}
__global__ __launch_bounds__(256) void k_scan_add(int* __restrict__ cursor, const int* __restrict__ blocksum) {
    int i = blockIdx.x * 256 + threadIdx.x;
    if (i < N_NODES) cursor[i] += blocksum[i >> 8];
}

// ---------------- K3: CSR scatter ----------------
__global__ __launch_bounds__(256) void k_scatter(const int* __restrict__ src, int* __restrict__ cursor,
                                                 int* __restrict__ eperm) {
    int e = blockIdx.x * 256 + threadIdx.x;
    if (e < N_EDGES) {
        int p = atomicAdd(&cursor[src[e]], 1);
        if (p >= 0 && p < N_EDGES) eperm[p] = e;
    }
}

// ---------------- K4: edge MLP (double-bf16 MFMA) + moment accumulation ----------------
__global__ __launch_bounds__(256) void k_msg(
    const float* __restrict__ x_t, const float* __restrict__ edge_attr,
    const float* __restrict__ w1a, const float* __restrict__ b1a,
    const float* __restrict__ w2a, const float* __restrict__ b2a,
    const int* __restrict__ src, const int* __restrict__ tgt,
    const int* __restrict__ eperm, float* __restrict__ S)
{
    __shared__ __align__(16) float h_lds[4][16][36];     // fp32 h, padded row (144B)
    __shared__ f32x4 pow_lds[64 * 32];                   // [row][col] -> {m,m2,m3,m4}
    __shared__ int nid_lds[64];
    const int t = threadIdx.x;
    const int w = t >> 6, L = t & 63, q = L >> 4, c = L & 15;

    // B-fragments (bf16 weights): B[k=q*8+j][n=c+16h]
    bf16x8 B1[2], B2[2];
    #pragma unroll
    for (int h = 0; h < 2; h++) {
        FU u1, u2;
        #pragma unroll
        for (int j = 0; j < 8; j++) {
            int k = q * 8 + j, n = c + 16 * h;
            u1.s[j] = f2bf(w1a[k * 32 + n]);
            u2.s[j] = f2bf(w2a[k * 32 + n]);
        }
        B1[h] = u1.v; B2[h] = u2.v;
    }
    const float bias1[2] = { b1a[c], b1a[c + 16] };
    const float bias2[2] = { b2a[c], b2a[c + 16] };
    const f32x4 zero = { 0.f, 0.f, 0.f, 0.f };

    for (int cb = blockIdx.x; cb < N_EDGES / 64; cb += gridDim.x) {
        const int B0 = cb * 64;
        if (t < 64) {
            int e0 = clampi(eperm[B0 + t], N_EDGES);
            nid_lds[t] = src[e0];
        }

        const int p = B0 + w * 16 + c;
        const int e = clampi(eperm[p], N_EDGES);
        float xv[8];
        if (q < 2) {
            int tg = clampi(tgt[e], N_NODES);
            #pragma unroll
            for (int j = 0; j < 8; j++) xv[j] = x_t[(size_t)tg * 16 + q * 8 + j];
        } else {
            #pragma unroll
            for (int j = 0; j < 8; j++) xv[j] = edge_attr[(size_t)e * 16 + (q - 2) * 8 + j];
        }
        bf16x8 Ah, Al;
        split8(xv, Ah, Al);
        f32x4 a0 = __builtin_amdgcn_mfma_f32_16x16x32_bf16(Al, B1[0], zero, 0, 0, 0);
        a0       = __builtin_amdgcn_mfma_f32_16x16x32_bf16(Ah, B1[0], a0,   0, 0, 0);
        f32x4 a1 = __builtin_amdgcn_mfma_f32_16x16x32_bf16(Al, B1[1], zero, 0, 0, 0);
        a1       = __builtin_amdgcn_mfma_f32_16x16x32_bf16(Ah, B1[1], a1,   0, 0, 0);
        #pragma unroll
        for (int r = 0; r < 4; r++) {
            h_lds[w][q * 4 + r][c]      = leaky(a0[r] + bias1[0], 0.1f);
            h_lds[w][q * 4 + r][c + 16] = leaky(a1[r] + bias1[1], 0.1f);
        }
        __syncthreads();
        float hv[8];
        #pragma unroll
        for (int j = 0; j < 8; j++) hv[j] = h_lds[w][c][q * 8 + j];
        bf16x8 Hh, Hl;
        split8(hv, Hh, Hl);
        f32x4 m0 = __builtin_amdgcn_mfma_f32_16x16x32_bf16(Hl, B2[0], zero, 0, 0, 0);
        m0       = __builtin_amdgcn_mfma_f32_16x16x32_bf16(Hh, B2[0], m0,   0, 0, 0);
        f32x4 m1 = __builtin_amdgcn_mfma_f32_16x16x32_bf16(Hl, B2[1], zero, 0, 0, 0);
        m1       = __builtin_amdgcn_mfma_f32_16x16x32_bf16(Hh, B2[1], m1,   0, 0, 0);
        #pragma unroll
        for (int r = 0; r < 4; r++) {
            int row = w * 16 + q * 4 + r;
            float m = m0[r] + bias2[0];
            m = fminf(fmaxf(m, -1e6f), 1e6f);
            float mm = m * m;
            pow_lds[row * 32 + c] = (f32x4){ m, mm, mm * m, mm * mm };
            float n2 = m1[r] + bias2[1];
            n2 = fminf(fmaxf(n2, -1e6f), 1e6f);
            float nn = n2 * n2;
            pow_lds[row * 32 + c + 16] = (f32x4){ n2, nn, nn * n2, nn * nn };
        }
        __syncthreads();
        if (t < 128) {
            const int f = t & 31, mo = t >> 5;
            const float* pw = (const float*)pow_lds;
            float s = 0.f; int prev = nid_lds[0];
            for (int r = 0; r < 64; r++) {
                int nid = nid_lds[r];
                if (nid != prev) {
                    unsafeAtomicAdd(S + (size_t)mo * N_NODES * 32 + (size_t)prev * 32 + f, s);
                    s = 0.f; prev = nid;
                }
                s += pw[(r * 32 + f) * 4 + mo];
            }
            unsafeAtomicAdd(S + (size_t)mo * N_NODES * 32 + (size_t)prev * 32 + f, s);
        }
        __syncthreads();
    }
}

// ---------------- K5: node features -> h_cat (fp32 [N,160]) ----------------
__global__ __launch_bounds__(256) void k_feat(
    const int* __restrict__ cnt, const float* __restrict__ S,
    const float* __restrict__ x_s, const float* __restrict__ u,
    float* __restrict__ hcat, float* __restrict__ bnsum)
{
    if (blockIdx.x == 0 && threadIdx.x < 32) bnsum[threadIdx.x] = 0.f;
    int idx = blockIdx.x * 256 + threadIdx.x;      // N_NODES*32 threads exactly
    int n = idx >> 5, f = idx & 31;
    float cv = (float)cnt[n];
    float denom = fmaxf(cv, 1.f);
    float s1 = S[(size_t)0 * N_NODES * 32 + n * 32 + f];
    float s2 = S[(size_t)1 * N_NODES * 32 + n * 32 + f];
    float s3 = S[(size_t)2 * N_NODES * 32 + n * 32 + f];
    float s4 = S[(size_t)3 * N_NODES * 32 + n * 32 + f];
    float mean = s1 / denom;
    float m2r = s2 / denom, m3r = s3 / denom, m4r = s4 / denom;
    float var0 = m2r - mean * mean;
    float var = leaky(var0, 0.01f);
    float stdv = sqrtf(var + 1e-6f);
    float e3 = m3r - 3.f * mean * m2r + 2.f * mean * mean * mean;
    float skew = e3 / (stdv * stdv * stdv);
    float e4 = m4r - 4.f * mean * m3r + 6.f * mean * mean * m2r - 3.f * mean * mean * mean * mean;
    float kurt = e4 / (stdv * stdv * stdv * stdv);
    size_t base = (size_t)n * 160;
    hcat[base + 16 + f]  = mean;
    hcat[base + 48 + f]  = stdv;
    hcat[base + 80 + f]  = skew;
    hcat[base + 112 + f] = kurt;
    if (f < 16) {
        hcat[base + f]       = x_s[(size_t)n * 16 + f];
        hcat[base + 144 + f] = u[f];
    }
}

// ---------------- K6: GEMM1 [N,160]@[160,160] + bias + leaky -> h2 (fp32) ----------------
__global__ __launch_bounds__(256) void k_gemm1(const float* __restrict__ hcat,
                                               const float* __restrict__ w1b,
                                               const float* __restrict__ b1b,
                                               float* __restrict__ h2)
{
    __shared__ __align__(16) ushort_t W1T[160 * 168];   // bf16 weights, transposed, padded rows
    int t = threadIdx.x;
    for (int i = t; i < 160 * 160; i += 256) { int k = i / 160, n = i % 160; W1T[n * 168 + k] = f2bf(w1b[i]); }
    __syncthreads();
    int w = t >> 6, L = t & 63, q = L >> 4, c = L & 15;
    const f32x4 zero = { 0.f, 0.f, 0.f, 0.f };
    for (int tile = blockIdx.x * 4 + w; tile < 3125 * 10; tile += gridDim.x * 4) {
        int rt = tile / 10, nt = tile % 10;
        int m = rt * 16 + c, n = nt * 16 + c;
        f32x4 acc = zero;
        #pragma unroll
        for (int ks = 0; ks < 5; ks++) {
            float av[8];
            #pragma unroll
            for (int j = 0; j < 8; j++) av[j] = hcat[(size_t)m * 160 + ks * 32 + q * 8 + j];
            bf16x8 Ahh, All;
            split8(av, Ahh, All);
            bf16x8 b; __builtin_memcpy(&b, &W1T[n * 168 + ks * 32 + q * 8], 16);
            acc = __builtin_amdgcn_mfma_f32_16x16x32_bf16(All, b, acc, 0, 0, 0);
            acc = __builtin_amdgcn_mfma_f32_16x16x32_bf16(Ahh, b, acc, 0, 0, 0);
        }
        float bias = b1b[n];
        #pragma unroll
        for (int r = 0; r < 4; r++) {
            h2[(size_t)(rt * 16 + q * 4 + r) * 160 + n] = leaky(acc[r] + bias, 0.1f);
        }
    }
}

// ---------------- K7: GEMM2 [N,160]@[160,16] + bias -> outpre (fp32) + BN partials ----------------
__global__ __launch_bounds__(256) void k_gemm2(const float* __restrict__ h2,
                                               const float* __restrict__ w2b,
                                               const float* __restrict__ b2b,
                                               float* __restrict__ outpre, float* __restrict__ bnsum)
{
    __shared__ __align__(16) ushort_t W2T[16 * 168];
    int t = threadIdx.x;
    for (int i = t; i < 160 * 16; i += 256) { int k = i / 16, n = i % 16; W2T[n * 168 + k] = f2bf(w2b[i]); }
    __syncthreads();
    int w = t >> 6, L = t & 63, q = L >> 4, c = L & 15;
    const f32x4 zero = { 0.f, 0.f, 0.f, 0.f };
    float ps = 0.f, ps2 = 0.f;
    float bias = b2b[c];
    for (int rt = blockIdx.x * 4 + w; rt < 3125; rt += gridDim.x * 4) {
        int m = rt * 16 + c;
        f32x4 acc = zero;
        #pragma unroll
        for (int ks = 0; ks < 5; ks++) {
            float av[8];
            #pragma unroll
            for (int j = 0; j < 8; j++) av[j] = h2[(size_t)m * 160 + ks * 32 + q * 8 + j];
            bf16x8 Ahh, All;
            split8(av, Ahh, All);
            bf16x8 b; __builtin_memcpy(&b, &W2T[c * 168 + ks * 32 + q * 8], 16);
            acc = __builtin_amdgcn_mfma_f32_16x16x32_bf16(All, b, acc, 0, 0, 0);
            acc = __builtin_amdgcn_mfma_f32_16x16x32_bf16(Ahh, b, acc, 0, 0, 0);
        }
        #pragma unroll
        for (int r = 0; r < 4; r++) {
            float v = acc[r] + bias;
            outpre[(size_t)(rt * 16 + q * 4 + r) * 16 + c] = v;
            ps += v; ps2 += v * v;
        }
    }
    ps  += __shfl_xor(ps, 16);  ps  += __shfl_xor(ps, 32);
    ps2 += __shfl_xor(ps2, 16); ps2 += __shfl_xor(ps2, 32);
    if (q == 0) {
        unsafeAtomicAdd(&bnsum[c], ps);
        unsafeAtomicAdd(&bnsum[16 + c], ps2);
    }
}

// ---------------- K8: BatchNorm apply -> d_out (fp32) ----------------
__global__ __launch_bounds__(256) void k_bn(const float* __restrict__ outpre, const float* __restrict__ bnsum,
                                            const float* __restrict__ gamma, const float* __restrict__ beta,
                                            float* __restrict__ out)
{
    int i = blockIdx.x * 256 + threadIdx.x;        // 800000 threads exactly
    int c = i & 15;
    float x = outpre[i];
    float mu = bnsum[c] * (1.f / N_NODES);
    float var = bnsum[16 + c] * (1.f / N_NODES) - mu * mu;
    out[i] = gamma[c] * (x - mu) * rsqrtf(var + 1e-5f) + beta[c];
}

// ---------------- launch ----------------
extern "C" void kernel_launch(void* const* d_in, const int* in_sizes, int n_in,
                              void* d_out, int out_size, void* d_ws, size_t ws_size,
                              hipStream_t stream) {
    const float* x_s  = (const float*)d_in[0];
    const float* x_t  = (const float*)d_in[1];
    const float* ea   = (const float*)d_in[2];
    const float* u    = (const float*)d_in[3];
    const float* w1a  = (const float*)d_in[4];
    const float* b1a  = (const float*)d_in[5];
    const float* w2a  = (const float*)d_in[6];
    const float* b2a  = (const float*)d_in[7];
    const float* w1b  = (const float*)d_in[8];
    const float* b1b  = (const float*)d_in[9];
    const float* w2b  = (const float*)d_in[10];
    const float* b2b  = (const float*)d_in[11];
    const float* gam  = (const float*)d_in[12];
    const float* bet  = (const float*)d_in[13];
    const int* eidx   = (const int*)d_in[14];
    const int* src = eidx;
    const int* tgt = eidx + N_EDGES;

    char* ws = (char*)d_ws;
    // workspace layout (bytes). NO aliasing within any live range:
    //   cnt     [0         , 200,192)   int[50000], dead after k_feat
    //   S       [200,192   , 25,800,192) float[4][50000][32], dead after k_feat
    //   cursor  [25,800,192, 26,000,384) int[50000] (+pad), dead after k_scatter
    //   blksum  [26,000,384, 26,001,408) int[256], dead after k_scan_add
    //   eperm   [26,001,408, 32,401,408) int[1.6M], dead after k_msg
    //   hcat    [32,401,408, 64,401,408) float[50000*160], dead after k_gemm1
    //   bnsum   [64,401,408, 64,401,536) float[32]
    //   outpre  [64,401,536, 67,601,536) float[800000]
    //   h2      [0         , 32,000,000) float[50000*160] OVERLAY of cnt/S/cursor/blksum/eperm[..],
    //           written by k_gemm1 (all overlaid buffers dead by then)
    const size_t OFF_CNT    = 0;
    const size_t OFF_S      = 200192;
    const size_t ZERO_BYTES = 25800192;       // memset: cnt + S
    const size_t OFF_CURSOR = 25800192;
    const size_t OFF_BLKSUM = 26000384;
    const size_t OFF_EPERM  = 26001408;
    const size_t OFF_HCAT   = 32401408;
    const size_t OFF_BNSUM  = 64401408;
    const size_t OFF_OUTPRE = 64401536;
    const size_t OFF_H2     = 0;

    int*   cnt     = (int*)(ws + OFF_CNT);
    float* S       = (float*)(ws + OFF_S);
    int*   cursor  = (int*)(ws + OFF_CURSOR);
    int*   blksum  = (int*)(ws + OFF_BLKSUM);
    int*   eperm   = (int*)(ws + OFF_EPERM);
    float* hcat    = (float*)(ws + OFF_HCAT);
    float* bnsum   = (float*)(ws + OFF_BNSUM);
    float* outpre  = (float*)(ws + OFF_OUTPRE);
    float* h2      = (float*)(ws + OFF_H2);

    hipMemsetAsync(ws, 0, ZERO_BYTES, stream);

    k_hist<<<(N_EDGES + 255) / 256, 256, 0, stream>>>(src, cnt);
    k_scan_chunk<<<NCHUNK, 256, 0, stream>>>(cnt, cursor, blksum);
    k_scan_block<<<1, 256, 0, stream>>>(blksum);
    k_scan_add<<<NCHUNK, 256, 0, stream>>>(cursor, blksum);
    k_scatter<<<(N_EDGES + 255) / 256, 256, 0, stream>>>(src, cursor, eperm);
    k_msg<<<2048, 256, 0, stream>>>(x_t, ea, w1a, b1a, w2a, b2a, src, tgt, eperm, S);
    k_feat<<<(N_NODES * 32) / 256, 256, 0, stream>>>(cnt, S, x_s, u, hcat, bnsum);
    k_gemm1<<<1024, 256, 0, stream>>>(hcat, w1b, b1b, h2);
    k_gemm2<<<256, 256, 0, stream>>>(h2, w2b, b2b, outpre, bnsum);
    k_bn<<<(N_NODES * 16) / 256, 256, 0, stream>>>(outpre, bnsum, gam, bet, (float*)d_out);
}

// Round 4
// 520.735 us; speedup vs baseline: 1.3484x; 1.3484x over previous
//
#include <hip/hip_runtime.h>

#define N_NODES 50000
#define N_EDGES 1600000
#define NCHUNK  ((N_NODES + 255) / 256)   // 196
#define NN32    (N_NODES * 32)

typedef unsigned short ushort_t;
typedef __attribute__((ext_vector_type(8))) __bf16 bf16x8;
typedef __attribute__((ext_vector_type(4))) float  f32x4;

union FU { ushort_t s[8]; bf16x8 v; };

__device__ __forceinline__ float bf2f(ushort_t u) {
    union { unsigned int i; float f; } v; v.i = ((unsigned int)u) << 16; return v.f;
}
__device__ __forceinline__ ushort_t f2bf(float f) {
    union { float f; unsigned int i; } v; v.f = f;
    unsigned int r = v.i + 0x7fffu + ((v.i >> 16) & 1u);
    return (ushort_t)(r >> 16);
}
__device__ __forceinline__ float leaky(float x, float s) { return x >= 0.f ? x : s * x; }

// ---------------- K1: histogram of src ----------------
__global__ __launch_bounds__(256) void k_hist(const int* __restrict__ src, int* __restrict__ cnt) {
    int e = blockIdx.x * 256 + threadIdx.x;
    if (e < N_EDGES) atomicAdd(&cnt[src[e]], 1);
}

// ---------------- K2: exclusive scan of cnt -> cursor ----------------
__global__ __launch_bounds__(256) void k_scan_chunk(const int* __restrict__ cnt, int* __restrict__ cursor,
                                                    int* __restrict__ blocksum) {
    __shared__ int buf[256];
    int t = threadIdx.x, i = blockIdx.x * 256 + t;
    int v = (i < N_NODES) ? cnt[i] : 0;
    buf[t] = v; __syncthreads();
    for (int off = 1; off < 256; off <<= 1) {
        int x = (t >= off) ? buf[t - off] : 0;
        __syncthreads(); buf[t] += x; __syncthreads();
    }
    int incl = buf[t];
    if (i < N_NODES) cursor[i] = incl - v;
    if (t == 255) blocksum[blockIdx.x] = incl;
}
__global__ __launch_bounds__(256) void k_scan_block(int* __restrict__ blocksum) {
    __shared__ int buf[256];
    int t = threadIdx.x;
    int v = (t < NCHUNK) ? blocksum[t] : 0;
    buf[t] = v; __syncthreads();
    for (int off = 1; off < 256; off <<= 1) {
        int x = (t >= off) ? buf[t - off] : 0;
        __syncthreads(); buf[t] += x; __syncthreads();
    }
    blocksum[t] = buf[t] - v;   // exclusive
}
__global__ __launch_bounds__(256) void k_scan_add(int* __restrict__ cursor, const int* __restrict__ blocksum) {
    int i = blockIdx.x * 256 + threadIdx.x;
    if (i < N_NODES) cursor[i] += blocksum[i >> 8];
}

// ---------------- K3: CSR scatter -> meta {e, nid, tgt, 0} ----------------
__global__ __launch_bounds__(256) void k_scatter(const int* __restrict__ src, const int* __restrict__ tgt,
                                                 int* __restrict__ cursor, int4* __restrict__ meta) {
    int e = blockIdx.x * 256 + threadIdx.x;
    if (e < N_EDGES) {
        int s = src[e], tg = tgt[e];
        int p = atomicAdd(&cursor[s], 1);
        if (p >= 0 && p < N_EDGES) meta[p] = make_int4(e, s, tg, 0);
    }
}

// ---------------- K4: edge MLP (bf16 MFMA) + per-wave segmented moment reduce ----------------
// 4 waves/block; wave w owns 16 CSR-consecutive edges per window; NO barriers in the loop.
__global__ __launch_bounds__(256) void k_msg(
    const float* __restrict__ x_t, const float* __restrict__ edge_attr,
    const float* __restrict__ w1a, const float* __restrict__ b1a,
    const float* __restrict__ w2a, const float* __restrict__ b2a,
    const int4* __restrict__ meta, float* __restrict__ S)
{
    __shared__ __align__(16) float h_lds[4][16][36];   // per-wave h slice (row stride 144 B)
    __shared__ float msg_lds[4][16][33];               // per-wave msg slice (bank-clean reads)
    __shared__ int   nid_lds[4][16];
    const int t = threadIdx.x;
    const int w = t >> 6, L = t & 63, q = L >> 4, c = L & 15;

    // B-fragments (bf16 weights): B[k=q*8+j][n=c+16h]
    bf16x8 B1[2], B2[2];
    #pragma unroll
    for (int h = 0; h < 2; h++) {
        FU u1, u2;
        #pragma unroll
        for (int j = 0; j < 8; j++) {
            int k = q * 8 + j, n = c + 16 * h;
            u1.s[j] = f2bf(w1a[k * 32 + n]);
            u2.s[j] = f2bf(w2a[k * 32 + n]);
        }
        B1[h] = u1.v; B2[h] = u2.v;
    }
    const float bias1[2] = { b1a[c], b1a[c + 16] };
    const float bias2[2] = { b2a[c], b2a[c + 16] };
    const f32x4 zero = { 0.f, 0.f, 0.f, 0.f };

    for (int cb = blockIdx.x; cb < N_EDGES / 64; cb += gridDim.x) {
        const int B0 = cb * 64;
        const int p  = B0 + w * 16 + c;
        int4 md = meta[p];                       // {e, nid, tgt, 0} — coalesced-ish, L2-friendly
        if (q == 0) nid_lds[w][c] = md.y;

        const float* gp = (q < 2) ? (x_t + (size_t)md.z * 16 + q * 8)
                                  : (edge_attr + (size_t)md.x * 16 + (q - 2) * 8);
        FU af;
        #pragma unroll
        for (int j = 0; j < 8; j++) af.s[j] = f2bf(gp[j]);

        f32x4 a0 = __builtin_amdgcn_mfma_f32_16x16x32_bf16(af.v, B1[0], zero, 0, 0, 0);
        f32x4 a1 = __builtin_amdgcn_mfma_f32_16x16x32_bf16(af.v, B1[1], zero, 0, 0, 0);
        #pragma unroll
        for (int r = 0; r < 4; r++) {
            h_lds[w][q * 4 + r][c]      = leaky(a0[r] + bias1[0], 0.1f);
            h_lds[w][q * 4 + r][c + 16] = leaky(a1[r] + bias1[1], 0.1f);
        }
        __asm__ volatile("s_waitcnt lgkmcnt(0)" ::: "memory");   // wave-local LDS drain

        float hv[8];
        __builtin_memcpy(&hv, &h_lds[w][c][q * 8], 32);
        FU hf;
        #pragma unroll
        for (int j = 0; j < 8; j++) hf.s[j] = f2bf(hv[j]);
        f32x4 m0 = __builtin_amdgcn_mfma_f32_16x16x32_bf16(hf.v, B2[0], zero, 0, 0, 0);
        f32x4 m1 = __builtin_amdgcn_mfma_f32_16x16x32_bf16(hf.v, B2[1], zero, 0, 0, 0);
        #pragma unroll
        for (int r = 0; r < 4; r++) {
            float m  = fminf(fmaxf(m0[r] + bias2[0], -1e6f), 1e6f);
            float n2 = fminf(fmaxf(m1[r] + bias2[1], -1e6f), 1e6f);
            msg_lds[w][q * 4 + r][c]      = m;
            msg_lds[w][q * 4 + r][c + 16] = n2;
        }
        __asm__ volatile("s_waitcnt lgkmcnt(0)" ::: "memory");

        if (L < 32) {                            // 32 cols, serial 16-row segmented scan
            const int f = L;
            float s1 = 0.f, s2 = 0.f, s3 = 0.f, s4 = 0.f;
            int cur = nid_lds[w][0];
            #pragma unroll
            for (int i = 0; i < 16; i++) {
                int nid = nid_lds[w][i];
                float m = msg_lds[w][i][f];      // bank = (i+f)%32 within wave: conflict-free
                if (nid != cur) {
                    size_t b = (size_t)cur * 32 + f;
                    unsafeAtomicAdd(S + b, s1);
                    unsafeAtomicAdd(S + NN32 + b, s2);
                    unsafeAtomicAdd(S + 2 * (size_t)NN32 + b, s3);
                    unsafeAtomicAdd(S + 3 * (size_t)NN32 + b, s4);
                    s1 = s2 = s3 = s4 = 0.f; cur = nid;
                }
                float mm = m * m;
                s1 += m; s2 += mm; s3 += mm * m; s4 += mm * mm;
            }
            size_t b = (size_t)cur * 32 + f;
            unsafeAtomicAdd(S + b, s1);
            unsafeAtomicAdd(S + NN32 + b, s2);
            unsafeAtomicAdd(S + 2 * (size_t)NN32 + b, s3);
            unsafeAtomicAdd(S + 3 * (size_t)NN32 + b, s4);
        }
        // no __syncthreads: all LDS slices are wave-private; DS ops are in-order per wave
    }
}

// ---------------- K5: node features -> h_cat (bf16 [N,160]) ----------------
__global__ __launch_bounds__(256) void k_feat(
    const int* __restrict__ cnt, const float* __restrict__ S,
    const float* __restrict__ x_s, const float* __restrict__ u,
    ushort_t* __restrict__ hcat, float* __restrict__ bnsum)
{
    if (blockIdx.x == 0 && threadIdx.x < 32) bnsum[threadIdx.x] = 0.f;
    int idx = blockIdx.x * 256 + threadIdx.x;      // N_NODES*32 threads exactly
    int n = idx >> 5, f = idx & 31;
    float cv = (float)cnt[n];
    float denom = fmaxf(cv, 1.f);
    float s1 = S[(size_t)0 * NN32 + n * 32 + f];
    float s2 = S[(size_t)1 * NN32 + n * 32 + f];
    float s3 = S[(size_t)2 * NN32 + n * 32 + f];
    float s4 = S[(size_t)3 * NN32 + n * 32 + f];
    float mean = s1 / denom;
    float m2r = s2 / denom, m3r = s3 / denom, m4r = s4 / denom;
    float var0 = m2r - mean * mean;
    float var = leaky(var0, 0.01f);
    float stdv = sqrtf(var + 1e-6f);
    float e3 = m3r - 3.f * mean * m2r + 2.f * mean * mean * mean;
    float skew = e3 / (stdv * stdv * stdv);
    float e4 = m4r - 4.f * mean * m3r + 6.f * mean * mean * m2r - 3.f * mean * mean * mean * mean;
    float kurt = e4 / (stdv * stdv * stdv * stdv);
    size_t base = (size_t)n * 160;
    hcat[base + 16 + f]  = f2bf(mean);
    hcat[base + 48 + f]  = f2bf(stdv);
    hcat[base + 80 + f]  = f2bf(skew);
    hcat[base + 112 + f] = f2bf(kurt);
    if (f < 16) {
        hcat[base + f]       = f2bf(x_s[(size_t)n * 16 + f]);
        hcat[base + 144 + f] = f2bf(u[f]);
    }
}

// ---------------- K6: GEMM1 [N,160]@[160,160] + bias + leaky -> h2 (bf16) ----------------
__global__ __launch_bounds__(256) void k_gemm1(const ushort_t* __restrict__ hcat,
                                               const float* __restrict__ w1b,
                                               const float* __restrict__ b1b,
                                               ushort_t* __restrict__ h2)
{
    __shared__ __align__(16) ushort_t W1T[160 * 168];   // bf16 weights, transposed, padded rows
    int t = threadIdx.x;
    for (int i = t; i < 160 * 160; i += 256) { int k = i / 160, n = i % 160; W1T[n * 168 + k] = f2bf(w1b[i]); }
    __syncthreads();
    int w = t >> 6, L = t & 63, q = L >> 4, c = L & 15;
    const f32x4 zero = { 0.f, 0.f, 0.f, 0.f };
    for (int tile = blockIdx.x * 4 + w; tile < 3125 * 10; tile += gridDim.x * 4) {
        int rt = tile / 10, nt = tile % 10;
        int m = rt * 16 + c, n = nt * 16 + c;
        f32x4 acc = zero;
        #pragma unroll
        for (int ks = 0; ks < 5; ks++) {
            bf16x8 a; __builtin_memcpy(&a, hcat + (size_t)m * 160 + ks * 32 + q * 8, 16);
            bf16x8 b; __builtin_memcpy(&b, &W1T[n * 168 + ks * 32 + q * 8], 16);
            acc = __builtin_amdgcn_mfma_f32_16x16x32_bf16(a, b, acc, 0, 0, 0);
        }
        float bias = b1b[n];
        #pragma unroll
        for (int r = 0; r < 4; r++) {
            h2[(size_t)(rt * 16 + q * 4 + r) * 160 + n] = f2bf(leaky(acc[r] + bias, 0.1f));
        }
    }
}

// ---------------- K7: GEMM2 [N,160]@[160,16] + bias -> outpre (fp32) + BN partials ----------------
__global__ __launch_bounds__(256) void k_gemm2(const ushort_t* __restrict__ h2,
                                               const float* __restrict__ w2b,
                                               const float* __restrict__ b2b,
                                               float* __restrict__ outpre, float* __restrict__ bnsum)
{
    __shared__ __align__(16) ushort_t W2T[16 * 168];
    int t = threadIdx.x;
    for (int i = t; i < 160 * 16; i += 256) { int k = i / 16, n = i % 16; W2T[n * 168 + k] = f2bf(w2b[i]); }
    __syncthreads();
    int w = t >> 6, L = t & 63, q = L >> 4, c = L & 15;
    const f32x4 zero = { 0.f, 0.f, 0.f, 0.f };
    float ps = 0.f, ps2 = 0.f;
    float bias = b2b[c];
    for (int rt = blockIdx.x * 4 + w; rt < 3125; rt += gridDim.x * 4) {
        int m = rt * 16 + c;
        f32x4 acc = zero;
        #pragma unroll
        for (int ks = 0; ks < 5; ks++) {
            bf16x8 a; __builtin_memcpy(&a, h2 + (size_t)m * 160 + ks * 32 + q * 8, 16);
            bf16x8 b; __builtin_memcpy(&b, &W2T[c * 168 + ks * 32 + q * 8], 16);
            acc = __builtin_amdgcn_mfma_f32_16x16x32_bf16(a, b, acc, 0, 0, 0);
        }
        #pragma unroll
        for (int r = 0; r < 4; r++) {
            float v = acc[r] + bias;
            outpre[(size_t)(rt * 16 + q * 4 + r) * 16 + c] = v;
            ps += v; ps2 += v * v;
        }
    }
    ps  += __shfl_xor(ps, 16);  ps  += __shfl_xor(ps, 32);
    ps2 += __shfl_xor(ps2, 16); ps2 += __shfl_xor(ps2, 32);
    if (q == 0) {
        unsafeAtomicAdd(&bnsum[c], ps);
        unsafeAtomicAdd(&bnsum[16 + c], ps2);
    }
}

// ---------------- K8: BatchNorm apply -> d_out (fp32) ----------------
__global__ __launch_bounds__(256) void k_bn(const float* __restrict__ outpre, const float* __restrict__ bnsum,
                                            const float* __restrict__ gamma, const float* __restrict__ beta,
                                            float* __restrict__ out)
{
    int i = blockIdx.x * 256 + threadIdx.x;        // 800000 threads exactly
    int c = i & 15;
    float x = outpre[i];
    float mu = bnsum[c] * (1.f / N_NODES);
    float var = bnsum[16 + c] * (1.f / N_NODES) - mu * mu;
    out[i] = gamma[c] * (x - mu) * rsqrtf(var + 1e-5f) + beta[c];
}

// ---------------- launch ----------------
extern "C" void kernel_launch(void* const* d_in, const int* in_sizes, int n_in,
                              void* d_out, int out_size, void* d_ws, size_t ws_size,
                              hipStream_t stream) {
    const float* x_s  = (const float*)d_in[0];
    const float* x_t  = (const float*)d_in[1];
    const float* ea   = (const float*)d_in[2];
    const float* u    = (const float*)d_in[3];
    const float* w1a  = (const float*)d_in[4];
    const float* b1a  = (const float*)d_in[5];
    const float* w2a  = (const float*)d_in[6];
    const float* b2a  = (const float*)d_in[7];
    const float* w1b  = (const float*)d_in[8];
    const float* b1b  = (const float*)d_in[9];
    const float* w2b  = (const float*)d_in[10];
    const float* b2b  = (const float*)d_in[11];
    const float* gam  = (const float*)d_in[12];
    const float* bet  = (const float*)d_in[13];
    const int* eidx   = (const int*)d_in[14];
    const int* src = eidx;
    const int* tgt = eidx + N_EDGES;

    char* ws = (char*)d_ws;
    // workspace layout (bytes) — live ranges, no aliasing within any:
    //   S       [0         , 25,600,000) fp32 moments, zeroed; live k_msg -> k_feat
    //   cnt     [25,600,000, 25,800,192) int[50000] (+pad), zeroed; live k_hist -> k_feat
    //   meta    [25,800,192, 51,400,192) int4[1.6M]; live k_scatter -> k_msg
    //   cursor  [51,400,192, 51,600,384) int[50000] (+pad); live scan -> k_scatter
    //   blksum  [51,600,384, 51,601,408) int[256]
    //   bnsum   [51,601,408, 51,601,536) float[32]
    //   outpre  [51,601,536, 54,801,536) float[800000]
    //   hcat    [25,800,192, 41,800,192) bf16[50000*160] OVERLAY meta (dead after k_msg)
    //   h2      [0         , 16,000,000) bf16[50000*160] OVERLAY S (dead after k_feat)
    const size_t OFF_S      = 0;
    const size_t OFF_CNT    = 25600000;
    const size_t ZERO_BYTES = 25800192;
    const size_t OFF_META   = 25800192;
    const size_t OFF_CURSOR = 51400192;
    const size_t OFF_BLKSUM = 51600384;
    const size_t OFF_BNSUM  = 51601408;
    const size_t OFF_OUTPRE = 51601536;
    const size_t OFF_HCAT   = 25800192;
    const size_t OFF_H2     = 0;

    float* S       = (float*)(ws + OFF_S);
    int*   cnt     = (int*)(ws + OFF_CNT);
    int4*  meta    = (int4*)(ws + OFF_META);
    int*   cursor  = (int*)(ws + OFF_CURSOR);
    int*   blksum  = (int*)(ws + OFF_BLKSUM);
    float* bnsum   = (float*)(ws + OFF_BNSUM);
    float* outpre  = (float*)(ws + OFF_OUTPRE);
    ushort_t* hcat = (ushort_t*)(ws + OFF_HCAT);
    ushort_t* h2   = (ushort_t*)(ws + OFF_H2);

    hipMemsetAsync(ws, 0, ZERO_BYTES, stream);

    k_hist<<<(N_EDGES + 255) / 256, 256, 0, stream>>>(src, cnt);
    k_scan_chunk<<<NCHUNK, 256, 0, stream>>>(cnt, cursor, blksum);
    k_scan_block<<<1, 256, 0, stream>>>(blksum);
    k_scan_add<<<NCHUNK, 256, 0, stream>>>(cursor, blksum);
    k_scatter<<<(N_EDGES + 255) / 256, 256, 0, stream>>>(src, tgt, cursor, meta);
    k_msg<<<1792, 256, 0, stream>>>(x_t, ea, w1a, b1a, w2a, b2a, meta, S);
    k_feat<<<(N_NODES * 32) / 256, 256, 0, stream>>>(cnt, S, x_s, u, hcat, bnsum);
    k_gemm1<<<1024, 256, 0, stream>>>(hcat, w1b, b1b, h2);
    k_gemm2<<<512, 256, 0, stream>>>(h2, w2b, b2b, outpre, bnsum);
    k_bn<<<(N_NODES * 16) / 256, 256, 0, stream>>>(outpre, bnsum, gam, bet, (float*)d_out);
}